// Round 2
// baseline (2177.393 us; speedup 1.0000x reference)
//
#include <hip/hip_runtime.h>
#include <hip/hip_bf16.h>
#include <cstdint>

// Problem constants
#define NROWS 65536
#define TTREAT 2

typedef __bf16 bf16x8 __attribute__((ext_vector_type(8)));
typedef float f32x4 __attribute__((ext_vector_type(4)));
typedef unsigned short u16;
typedef u16 u16x8 __attribute__((ext_vector_type(8)));

#define GLOBAL_AS __attribute__((address_space(1)))
#define LDS_AS __attribute__((address_space(3)))

__device__ __forceinline__ u16 f32_to_bf16_bits(float f) {
    union { float f; uint32_t u; } v; v.f = f;
    uint32_t u = v.u;
    return (u16)((u + 0x7FFFu + ((u >> 16) & 1u)) >> 16);
}

__device__ __forceinline__ float bf16_bits_to_f32(u16 b) {
    union { uint32_t u; float f; } v; v.u = ((uint32_t)b) << 16;
    return v.f;
}

// ---------------- elementwise conversion: f32 -> bf16 (8 elems/thread) -------
__global__ void cvt_f32_bf16(const float4* __restrict__ src, u16x8* __restrict__ dst, int n8) {
    int i = blockIdx.x * blockDim.x + threadIdx.x;
    if (i >= n8) return;
    float4 a = src[2 * i], b = src[2 * i + 1];
    u16x8 r;
    r[0] = f32_to_bf16_bits(a.x); r[1] = f32_to_bf16_bits(a.y);
    r[2] = f32_to_bf16_bits(a.z); r[3] = f32_to_bf16_bits(a.w);
    r[4] = f32_to_bf16_bits(b.x); r[5] = f32_to_bf16_bits(b.y);
    r[6] = f32_to_bf16_bits(b.z); r[7] = f32_to_bf16_bits(b.w);
    dst[i] = r;
}

// ---------------- weight transpose: src [K,M] f32 -> dst [M,K] bf16 ----------
// K, M multiples of 32. blockDim = (32,8). grid = (M/32, K/32, batch)
__global__ void transpose_w(const float* __restrict__ src, u16* __restrict__ dst, int K, int M) {
    __shared__ float tile[32][33];
    size_t boff = (size_t)blockIdx.z * K * M;
    src += boff; dst += boff;
    int m0 = blockIdx.x * 32, k0 = blockIdx.y * 32;
    int tx = threadIdx.x, ty = threadIdx.y;
#pragma unroll
    for (int i = 0; i < 32; i += 8)
        tile[ty + i][tx] = src[(size_t)(k0 + ty + i) * M + m0 + tx];
    __syncthreads();
#pragma unroll
    for (int i = 0; i < 32; i += 8)
        dst[(size_t)(m0 + ty + i) * K + k0 + tx] = f32_to_bf16_bits(tile[tx][ty + i]);
}

// ---------------- partition rows by treatment --------------------------------
__global__ void zero_cnt(int* cnt) {
    if (threadIdx.x < TTREAT) cnt[threadIdx.x] = 0;
}

__global__ void partition_rows(const int* __restrict__ treat, int* __restrict__ idx, int* __restrict__ cnt) {
    int i = blockIdx.x * 256 + threadIdx.x;
    if (i >= NROWS) return;
    int t = treat[i];
    int pos = atomicAdd(&cnt[t], 1);
    idx[t * NROWS + pos] = i;
}

// ---------------- main GEMM: C = relu(A @ Bt^T + bias) -----------------------
// Operates on a row-chunk: logical rows [chunkStart, chunkStart+maxRows) of a
// row set whose total count is (*cntp) or nrows. Local row r in [0, rows_eff).
// A: bf16. GATHER: A row = idx[r] (idx pre-offset by chunkStart), A has full-N
// rows. !GATHER: A row = r (A is the chunk-local buffer / pre-offset pointer).
// Bt: [M, K] bf16 (transposed weight), bias: [M] f32
// C: [*, M] bf16 (chunk-local / pre-offset); optionally also C32 f32.
// 128x128 tile, BK=64, 256 threads (4 waves as 2x2 of 64x64)
template <bool GATHER, bool WRITE_F32>
__global__ void gemm_bias_relu(const u16* __restrict__ A, const u16* __restrict__ Bt,
                               const float* __restrict__ bias,
                               u16* __restrict__ C, float* __restrict__ C32,
                               const int* __restrict__ idx, const int* __restrict__ cntp,
                               int nrows, int chunkStart, int maxRows, int K, int M) {
    int rows = (cntp ? *cntp : nrows) - chunkStart;
    if (rows > maxRows) rows = maxRows;
    int rowBase = blockIdx.y * 128;
    if (rows <= 0 || rowBase >= rows) return;
    int colBase = blockIdx.x * 128;

    __shared__ __align__(16) u16 As[128 * 64];
    __shared__ __align__(16) u16 Bs[128 * 64];

    const int tid = threadIdx.x;
    const int wave = tid >> 6, lane = tid & 63;
    const int quad = lane >> 4, l16 = lane & 15;
    const int wm = wave >> 1, wn = wave & 1;

    // staging geometry: chunk c = it*256 + tid; row = c>>3; k elem = (c&7)*8
    const int r0 = tid >> 3;          // 0..31
    const int kc = (tid & 7) * 8;     // 0..56

    size_t a_off[4], b_off[4];
#pragma unroll
    for (int it = 0; it < 4; ++it) {
        int r = rowBase + r0 + it * 32;
        int grow;
        if (GATHER) {
            int rc = r < rows ? r : (rows - 1);
            grow = idx[rc];
        } else {
            grow = r;   // chunk-local buffer has maxRows rows; garbage rows discarded
        }
        a_off[it] = (size_t)grow * K + kc;
        int c = colBase + r0 + it * 32;   // always < M (M multiple of 128)
        b_off[it] = (size_t)c * K + kc;
    }

    f32x4 acc[4][4] = {};

    for (int k0 = 0; k0 < K; k0 += 64) {
        __syncthreads();
#pragma unroll
        for (int it = 0; it < 4; ++it) {
            __builtin_amdgcn_global_load_lds(
                (const GLOBAL_AS void*)(A + a_off[it] + k0),
                (LDS_AS void*)(&As[(it * 256 + wave * 64) * 8]), 16, 0, 0);
            __builtin_amdgcn_global_load_lds(
                (const GLOBAL_AS void*)(Bt + b_off[it] + k0),
                (LDS_AS void*)(&Bs[(it * 256 + wave * 64) * 8]), 16, 0, 0);
        }
        __syncthreads();
#pragma unroll
        for (int kk = 0; kk < 2; ++kk) {
            bf16x8 aF[4], bF[4];
            const int ko = kk * 32 + quad * 8;
#pragma unroll
            for (int mi = 0; mi < 4; ++mi)
                aF[mi] = *(const bf16x8*)&As[(wm * 64 + mi * 16 + l16) * 64 + ko];
#pragma unroll
            for (int ni = 0; ni < 4; ++ni)
                bF[ni] = *(const bf16x8*)&Bs[(wn * 64 + ni * 16 + l16) * 64 + ko];
#pragma unroll
            for (int mi = 0; mi < 4; ++mi)
#pragma unroll
                for (int ni = 0; ni < 4; ++ni)
                    acc[mi][ni] = __builtin_amdgcn_mfma_f32_16x16x32_bf16(
                        aF[mi], bF[ni], acc[mi][ni], 0, 0, 0);
        }
    }

    // epilogue: bias + relu, store bf16 (and optional f32)
    float bv[4];
#pragma unroll
    for (int ni = 0; ni < 4; ++ni) bv[ni] = bias[colBase + wn * 64 + ni * 16 + l16];

#pragma unroll
    for (int mi = 0; mi < 4; ++mi) {
        int rloc = rowBase + wm * 64 + mi * 16 + quad * 4;
#pragma unroll
        for (int ni = 0; ni < 4; ++ni) {
            int col = colBase + wn * 64 + ni * 16 + l16;
#pragma unroll
            for (int r = 0; r < 4; ++r) {
                int row = rloc + r;
                if (row < rows) {
                    float v = acc[mi][ni][r] + bv[ni];
                    v = v > 0.f ? v : 0.f;
                    C[(size_t)row * M + col] = f32_to_bf16_bits(v);
                    if (WRITE_F32) C32[(size_t)row * M + col] = v;
                }
            }
        }
    }
}

// ---------------- head: y[idx[pos]] = dot(g2[pos], Wo) + bo ------------------
// one wave per chunk-local row; 4 waves per block
__global__ void head_kernel(const u16* __restrict__ g2, const int* __restrict__ idx,
                            const int* __restrict__ cntp, int chunkStart, int maxRows,
                            const float* __restrict__ Wo,
                            const float* __restrict__ bo, float* __restrict__ y) {
    int rows = *cntp - chunkStart;
    if (rows > maxRows) rows = maxRows;
    int wave = threadIdx.x >> 6, lane = threadIdx.x & 63;
    int pos = blockIdx.x * 4 + wave;
    if (pos >= rows) return;
    const u16* grow = g2 + (size_t)pos * 512;
    u16x8 gv = *(const u16x8*)&grow[lane * 8];
    const float4* w4 = (const float4*)Wo + lane * 2;
    float4 w0 = w4[0], w1 = w4[1];
    float s = 0.f;
    s += bf16_bits_to_f32(gv[0]) * w0.x + bf16_bits_to_f32(gv[1]) * w0.y;
    s += bf16_bits_to_f32(gv[2]) * w0.z + bf16_bits_to_f32(gv[3]) * w0.w;
    s += bf16_bits_to_f32(gv[4]) * w1.x + bf16_bits_to_f32(gv[5]) * w1.y;
    s += bf16_bits_to_f32(gv[6]) * w1.z + bf16_bits_to_f32(gv[7]) * w1.w;
#pragma unroll
    for (int off = 32; off > 0; off >>= 1) s += __shfl_down(s, off);
    if (lane == 0) y[idx[pos]] = s + bo[0];
}

// ---------------- t_out: softmax over size-1 axis == 1.0 ---------------------
__global__ void ones_kernel(float* __restrict__ dst, int n) {
    int i = blockIdx.x * 256 + threadIdx.x;
    if (i < n) dst[i] = 1.0f;
}

extern "C" void kernel_launch(void* const* d_in, const int* in_sizes, int n_in,
                              void* d_out, int out_size, void* d_ws, size_t ws_size,
                              hipStream_t stream) {
    const float* x   = (const float*)d_in[0];
    const int* treat = (const int*)d_in[1];
    const float* Wx0 = (const float*)d_in[2];
    const float* bx0 = (const float*)d_in[3];
    const float* Wx1 = (const float*)d_in[4];
    const float* bx1 = (const float*)d_in[5];
    const float* Wx2 = (const float*)d_in[6];
    const float* bx2 = (const float*)d_in[7];
    const float* Wy0 = (const float*)d_in[8];
    const float* by0 = (const float*)d_in[9];
    const float* Wy1 = (const float*)d_in[10];
    const float* by1 = (const float*)d_in[11];
    const float* Wo  = (const float*)d_in[12];
    const float* bo  = (const float*)d_in[13];
    // Wt (14), bt (15) unused: softmax over size-1 axis == 1 exactly

    float* out_y  = (float*)d_out;                       // [N]
    float* out_xe = out_y + NROWS;                       // [N, 512]
    float* out_t  = out_xe + (size_t)NROWS * 512;        // [N]

    // ---- choose row-chunk size R from ws_size (deterministic per process) ----
    // fixed residents: bf16 weights 16 MiB + xe 64 MiB + idx 0.5 MiB (+pad)
    const size_t FIXED = ((size_t)(2048 * 512 + 2048 * 2048 + 512 * 2048
                          + TTREAT * 1024 * 512 + TTREAT * 512 * 1024
                          + (size_t)NROWS * 512) * 2)                 // bf16 bufs
                          + (size_t)TTREAT * NROWS * 4 + (1 << 20);   // idx + slack
    int R = 512;
    const int cands[6] = {16384, 8192, 4096, 2048, 1024, 512};
    for (int ci = 0; ci < 6; ++ci) {
        // variable: xbc R*1024B + h1c R*4096B + h2c R*4096B + g1c R*2048B + g2c R*1024B
        if (FIXED + (size_t)cands[ci] * 12288 <= ws_size) { R = cands[ci]; break; }
    }
    const int NCHUNK = NROWS / R;

    // ---- workspace carve-up ----
    size_t off = 0;
    auto carve = [&](size_t bytes) {
        void* p = (char*)d_ws + off;
        off += (bytes + 255) & ~(size_t)255;
        return p;
    };
    u16* Wx0t = (u16*)carve((size_t)2048 * 512 * 2);
    u16* Wx1t = (u16*)carve((size_t)2048 * 2048 * 2);
    u16* Wx2t = (u16*)carve((size_t)512 * 2048 * 2);
    u16* Wy0t = (u16*)carve((size_t)TTREAT * 1024 * 512 * 2);
    u16* Wy1t = (u16*)carve((size_t)TTREAT * 512 * 1024 * 2);
    u16* xe   = (u16*)carve((size_t)NROWS * 512 * 2);        // full-N bf16 x_emb
    int* idx  = (int*)carve((size_t)TTREAT * NROWS * 4);
    int* cnt  = (int*)carve(256);
    u16* xbc  = (u16*)carve((size_t)R * 512 * 2);            // chunk x bf16
    u16* h1c  = (u16*)carve((size_t)R * 2048 * 2);
    u16* h2c  = (u16*)carve((size_t)R * 2048 * 2);
    u16* g1c  = (u16*)carve((size_t)R * 1024 * 2);
    u16* g2c  = (u16*)carve((size_t)R * 512 * 2);

    dim3 tb32(32, 8);

    // weight transposes (bf16, [M,K]) — once
    transpose_w<<<dim3(2048 / 32, 512 / 32, 1), tb32, 0, stream>>>(Wx0, Wx0t, 512, 2048);
    transpose_w<<<dim3(2048 / 32, 2048 / 32, 1), tb32, 0, stream>>>(Wx1, Wx1t, 2048, 2048);
    transpose_w<<<dim3(512 / 32, 2048 / 32, 1), tb32, 0, stream>>>(Wx2, Wx2t, 2048, 512);
    transpose_w<<<dim3(1024 / 32, 512 / 32, TTREAT), tb32, 0, stream>>>(Wy0, Wy0t, 512, 1024);
    transpose_w<<<dim3(512 / 32, 1024 / 32, TTREAT), tb32, 0, stream>>>(Wy1, Wy1t, 1024, 512);

    // partition rows by treatment — once
    zero_cnt<<<1, 64, 0, stream>>>(cnt);
    partition_rows<<<NROWS / 256, 256, 0, stream>>>(treat, idx, cnt);

    const int gy = R / 128;   // chunk-local row blocks

    // ---- trunk, chunked over rows ----
    for (int c = 0; c < NCHUNK; ++c) {
        int cS = c * R;
        cvt_f32_bf16<<<(R * 512 / 8 + 255) / 256, 256, 0, stream>>>(
            (const float4*)(x + (size_t)cS * 512), (u16x8*)xbc, R * 512 / 8);
        gemm_bias_relu<false, false><<<dim3(2048 / 128, gy), 256, 0, stream>>>(
            xbc, Wx0t, bx0, h1c, nullptr, nullptr, nullptr, NROWS, cS, R, 512, 2048);
        gemm_bias_relu<false, false><<<dim3(2048 / 128, gy), 256, 0, stream>>>(
            h1c, Wx1t, bx1, h2c, nullptr, nullptr, nullptr, NROWS, cS, R, 2048, 2048);
        gemm_bias_relu<false, true><<<dim3(512 / 128, gy), 256, 0, stream>>>(
            h2c, Wx2t, bx2, xe + (size_t)cS * 512, out_xe + (size_t)cS * 512,
            nullptr, nullptr, NROWS, cS, R, 2048, 512);
    }

    // ---- experts (only the selected treatment's rows), chunked ----
    for (int t = 0; t < TTREAT; ++t) {
        const int* idx_t = idx + (size_t)t * NROWS;
        for (int c = 0; c < NCHUNK; ++c) {
            int cS = c * R;
            gemm_bias_relu<true, false><<<dim3(1024 / 128, gy), 256, 0, stream>>>(
                xe, Wy0t + (size_t)t * 1024 * 512, by0 + (size_t)t * 1024,
                g1c, nullptr, idx_t + cS, cnt + t, NROWS, cS, R, 512, 1024);
            gemm_bias_relu<false, false><<<dim3(512 / 128, gy), 256, 0, stream>>>(
                g1c, Wy1t + (size_t)t * 512 * 1024, by1 + (size_t)t * 512,
                g2c, nullptr, nullptr, cnt + t, NROWS, cS, R, 1024, 512);
            head_kernel<<<R / 4, 256, 0, stream>>>(
                g2c, idx_t + cS, cnt + t, cS, R, Wo + (size_t)t * 512, bo + t, out_y);
        }
    }

    // t_out == softmax over size-1 axis == 1.0 exactly
    ones_kernel<<<NROWS / 256, 256, 0, stream>>>(out_t, NROWS);
}

// Round 3
// 1652.462 us; speedup vs baseline: 1.3177x; 1.3177x over previous
//
#include <hip/hip_runtime.h>
#include <hip/hip_bf16.h>
#include <cstdint>

// Problem constants
#define NROWS 65536
#define TTREAT 2

typedef __bf16 bf16x8 __attribute__((ext_vector_type(8)));
typedef float f32x4 __attribute__((ext_vector_type(4)));
typedef unsigned short u16;
typedef u16 u16x8 __attribute__((ext_vector_type(8)));

#define GLOBAL_AS __attribute__((address_space(1)))
#define LDS_AS __attribute__((address_space(3)))

__device__ __forceinline__ u16 f32_to_bf16_bits(float f) {
    union { float f; uint32_t u; } v; v.f = f;
    uint32_t u = v.u;
    return (u16)((u + 0x7FFFu + ((u >> 16) & 1u)) >> 16);
}

__device__ __forceinline__ float bf16_bits_to_f32(u16 b) {
    union { uint32_t u; float f; } v; v.u = ((uint32_t)b) << 16;
    return v.f;
}

// ---------------- elementwise conversion: f32 -> bf16 (8 elems/thread) -------
__global__ void cvt_f32_bf16(const float4* __restrict__ src, u16x8* __restrict__ dst, int n8) {
    int i = blockIdx.x * blockDim.x + threadIdx.x;
    if (i >= n8) return;
    float4 a = src[2 * i], b = src[2 * i + 1];
    u16x8 r;
    r[0] = f32_to_bf16_bits(a.x); r[1] = f32_to_bf16_bits(a.y);
    r[2] = f32_to_bf16_bits(a.z); r[3] = f32_to_bf16_bits(a.w);
    r[4] = f32_to_bf16_bits(b.x); r[5] = f32_to_bf16_bits(b.y);
    r[6] = f32_to_bf16_bits(b.z); r[7] = f32_to_bf16_bits(b.w);
    dst[i] = r;
}

// ---------------- weight transpose: src [K,M] f32 -> dst [M,K] bf16 ----------
// K, M multiples of 32. blockDim = (32,8). grid = (M/32, K/32, batch)
__global__ void transpose_w(const float* __restrict__ src, u16* __restrict__ dst, int K, int M) {
    __shared__ float tile[32][33];
    size_t boff = (size_t)blockIdx.z * K * M;
    src += boff; dst += boff;
    int m0 = blockIdx.x * 32, k0 = blockIdx.y * 32;
    int tx = threadIdx.x, ty = threadIdx.y;
#pragma unroll
    for (int i = 0; i < 32; i += 8)
        tile[ty + i][tx] = src[(size_t)(k0 + ty + i) * M + m0 + tx];
    __syncthreads();
#pragma unroll
    for (int i = 0; i < 32; i += 8)
        dst[(size_t)(m0 + ty + i) * K + k0 + tx] = f32_to_bf16_bits(tile[tx][ty + i]);
}

// ---------------- partition rows by treatment --------------------------------
__global__ void zero_cnt(int* cnt) {
    if (threadIdx.x < TTREAT) cnt[threadIdx.x] = 0;
}

// Hierarchical partition: wave ballot -> LDS wave counts -> 1 global atomic
// per treatment per block (512 total, vs 65536 flat). Order within a treatment
// is block-order-dependent, which is fine: idx is only a permutation.
__global__ void partition_rows(const int* __restrict__ treat, int* __restrict__ idx, int* __restrict__ cnt) {
    __shared__ int waveCnt1[4];
    __shared__ int blockBase[2];
    const int tid = threadIdx.x;
    const int i = blockIdx.x * 256 + tid;
    const int wave = tid >> 6, lane = tid & 63;
    const int t = treat[i];
    const unsigned long long m1 = __ballot(t == 1);
    const int n1 = __popcll(m1);
    if (lane == 0) waveCnt1[wave] = n1;
    __syncthreads();
    const int w0 = waveCnt1[0], w1 = waveCnt1[1], w2 = waveCnt1[2], w3 = waveCnt1[3];
    const int tot1 = w0 + w1 + w2 + w3;
    if (tid == 0) blockBase[0] = atomicAdd(&cnt[0], 256 - tot1);
    else if (tid == 64) blockBase[1] = atomicAdd(&cnt[1], tot1);
    __syncthreads();
    int waveOff1 = 0;
    if (wave > 0) waveOff1 += w0;
    if (wave > 1) waveOff1 += w1;
    if (wave > 2) waveOff1 += w2;
    const int below1 = (int)__popcll(m1 & ((1ull << lane) - 1ull));
    int pos;
    if (t == 1) pos = blockBase[1] + waveOff1 + below1;
    else        pos = blockBase[0] + (wave * 64 - waveOff1) + (lane - below1);
    idx[t * NROWS + pos] = i;
}

// ---------------- main GEMM: C = relu(A @ Bt^T + bias) -----------------------
// Operates on a row-chunk: logical rows [chunkStart, chunkStart+maxRows) of a
// row set whose total count is (*cntp) or nrows. Local row r in [0, rows_eff).
// A: bf16. GATHER: A row = idx[r] (idx pre-offset by chunkStart), A has full-N
// rows. !GATHER: A row = r (A is the chunk-local buffer / pre-offset pointer).
// Bt: [M, K] bf16 (transposed weight), bias: [M] f32
// C: [*, M] bf16 (chunk-local / pre-offset); optionally also C32 f32.
// 128x128 tile, BK=64, 256 threads (4 waves as 2x2 of 64x64)
template <bool GATHER, bool WRITE_F32>
__global__ void gemm_bias_relu(const u16* __restrict__ A, const u16* __restrict__ Bt,
                               const float* __restrict__ bias,
                               u16* __restrict__ C, float* __restrict__ C32,
                               const int* __restrict__ idx, const int* __restrict__ cntp,
                               int nrows, int chunkStart, int maxRows, int K, int M) {
    int rows = (cntp ? *cntp : nrows) - chunkStart;
    if (rows > maxRows) rows = maxRows;
    int rowBase = blockIdx.y * 128;
    if (rows <= 0 || rowBase >= rows) return;
    int colBase = blockIdx.x * 128;

    __shared__ __align__(16) u16 As[128 * 64];
    __shared__ __align__(16) u16 Bs[128 * 64];

    const int tid = threadIdx.x;
    const int wave = tid >> 6, lane = tid & 63;
    const int quad = lane >> 4, l16 = lane & 15;
    const int wm = wave >> 1, wn = wave & 1;

    // staging geometry: chunk c = it*256 + tid; row = c>>3; k elem = (c&7)*8
    const int r0 = tid >> 3;          // 0..31
    const int kc = (tid & 7) * 8;     // 0..56

    size_t a_off[4], b_off[4];
#pragma unroll
    for (int it = 0; it < 4; ++it) {
        int r = rowBase + r0 + it * 32;
        int grow;
        if (GATHER) {
            int rc = r < rows ? r : (rows - 1);
            grow = idx[rc];
        } else {
            grow = r;   // chunk-local buffer has maxRows rows; garbage rows discarded
        }
        a_off[it] = (size_t)grow * K + kc;
        int c = colBase + r0 + it * 32;   // always < M (M multiple of 128)
        b_off[it] = (size_t)c * K + kc;
    }

    f32x4 acc[4][4] = {};

    for (int k0 = 0; k0 < K; k0 += 64) {
        __syncthreads();
#pragma unroll
        for (int it = 0; it < 4; ++it) {
            __builtin_amdgcn_global_load_lds(
                (const GLOBAL_AS void*)(A + a_off[it] + k0),
                (LDS_AS void*)(&As[(it * 256 + wave * 64) * 8]), 16, 0, 0);
            __builtin_amdgcn_global_load_lds(
                (const GLOBAL_AS void*)(Bt + b_off[it] + k0),
                (LDS_AS void*)(&Bs[(it * 256 + wave * 64) * 8]), 16, 0, 0);
        }
        __syncthreads();
#pragma unroll
        for (int kk = 0; kk < 2; ++kk) {
            bf16x8 aF[4], bF[4];
            const int ko = kk * 32 + quad * 8;
#pragma unroll
            for (int mi = 0; mi < 4; ++mi)
                aF[mi] = *(const bf16x8*)&As[(wm * 64 + mi * 16 + l16) * 64 + ko];
#pragma unroll
            for (int ni = 0; ni < 4; ++ni)
                bF[ni] = *(const bf16x8*)&Bs[(wn * 64 + ni * 16 + l16) * 64 + ko];
#pragma unroll
            for (int mi = 0; mi < 4; ++mi)
#pragma unroll
                for (int ni = 0; ni < 4; ++ni)
                    acc[mi][ni] = __builtin_amdgcn_mfma_f32_16x16x32_bf16(
                        aF[mi], bF[ni], acc[mi][ni], 0, 0, 0);
        }
    }

    // epilogue: bias + relu, store bf16 (and optional f32)
    float bv[4];
#pragma unroll
    for (int ni = 0; ni < 4; ++ni) bv[ni] = bias[colBase + wn * 64 + ni * 16 + l16];

#pragma unroll
    for (int mi = 0; mi < 4; ++mi) {
        int rloc = rowBase + wm * 64 + mi * 16 + quad * 4;
#pragma unroll
        for (int ni = 0; ni < 4; ++ni) {
            int col = colBase + wn * 64 + ni * 16 + l16;
#pragma unroll
            for (int r = 0; r < 4; ++r) {
                int row = rloc + r;
                if (row < rows) {
                    float v = acc[mi][ni][r] + bv[ni];
                    v = v > 0.f ? v : 0.f;
                    C[(size_t)row * M + col] = f32_to_bf16_bits(v);
                    if (WRITE_F32) C32[(size_t)row * M + col] = v;
                }
            }
        }
    }
}

// ---------------- head: y[idx[pos]] = dot(g2[pos], Wo) + bo ------------------
// one wave per chunk-local row; 4 waves per block
__global__ void head_kernel(const u16* __restrict__ g2, const int* __restrict__ idx,
                            const int* __restrict__ cntp, int chunkStart, int maxRows,
                            const float* __restrict__ Wo,
                            const float* __restrict__ bo, float* __restrict__ y) {
    int rows = *cntp - chunkStart;
    if (rows > maxRows) rows = maxRows;
    int wave = threadIdx.x >> 6, lane = threadIdx.x & 63;
    int pos = blockIdx.x * 4 + wave;
    if (pos >= rows) return;
    const u16* grow = g2 + (size_t)pos * 512;
    u16x8 gv = *(const u16x8*)&grow[lane * 8];
    const float4* w4 = (const float4*)Wo + lane * 2;
    float4 w0 = w4[0], w1 = w4[1];
    float s = 0.f;
    s += bf16_bits_to_f32(gv[0]) * w0.x + bf16_bits_to_f32(gv[1]) * w0.y;
    s += bf16_bits_to_f32(gv[2]) * w0.z + bf16_bits_to_f32(gv[3]) * w0.w;
    s += bf16_bits_to_f32(gv[4]) * w1.x + bf16_bits_to_f32(gv[5]) * w1.y;
    s += bf16_bits_to_f32(gv[6]) * w1.z + bf16_bits_to_f32(gv[7]) * w1.w;
#pragma unroll
    for (int off = 32; off > 0; off >>= 1) s += __shfl_down(s, off);
    if (lane == 0) y[idx[pos]] = s + bo[0];
}

// ---------------- t_out: softmax over size-1 axis == 1.0 ---------------------
__global__ void ones_kernel(float* __restrict__ dst, int n) {
    int i = blockIdx.x * 256 + threadIdx.x;
    if (i < n) dst[i] = 1.0f;
}

extern "C" void kernel_launch(void* const* d_in, const int* in_sizes, int n_in,
                              void* d_out, int out_size, void* d_ws, size_t ws_size,
                              hipStream_t stream) {
    const float* x   = (const float*)d_in[0];
    const int* treat = (const int*)d_in[1];
    const float* Wx0 = (const float*)d_in[2];
    const float* bx0 = (const float*)d_in[3];
    const float* Wx1 = (const float*)d_in[4];
    const float* bx1 = (const float*)d_in[5];
    const float* Wx2 = (const float*)d_in[6];
    const float* bx2 = (const float*)d_in[7];
    const float* Wy0 = (const float*)d_in[8];
    const float* by0 = (const float*)d_in[9];
    const float* Wy1 = (const float*)d_in[10];
    const float* by1 = (const float*)d_in[11];
    const float* Wo  = (const float*)d_in[12];
    const float* bo  = (const float*)d_in[13];
    // Wt (14), bt (15) unused: softmax over size-1 axis == 1 exactly

    float* out_y  = (float*)d_out;                       // [N]
    float* out_xe = out_y + NROWS;                       // [N, 512]
    float* out_t  = out_xe + (size_t)NROWS * 512;        // [N]

    // ---- choose row-chunk size R from ws_size (deterministic per process) ----
    // fixed residents: bf16 weights 16 MiB + xe 64 MiB + idx 0.5 MiB (+pad)
    const size_t FIXED = ((size_t)(2048 * 512 + 2048 * 2048 + 512 * 2048
                          + TTREAT * 1024 * 512 + TTREAT * 512 * 1024
                          + (size_t)NROWS * 512) * 2)                 // bf16 bufs
                          + (size_t)TTREAT * NROWS * 4 + (1 << 20);   // idx + slack
    int R = 512;
    const int cands[6] = {16384, 8192, 4096, 2048, 1024, 512};
    for (int ci = 0; ci < 6; ++ci) {
        // variable: xbc R*1024B + h1c R*4096B + h2c R*4096B + g1c R*2048B + g2c R*1024B
        if (FIXED + (size_t)cands[ci] * 12288 <= ws_size) { R = cands[ci]; break; }
    }
    const int NCHUNK = NROWS / R;

    // ---- workspace carve-up ----
    size_t off = 0;
    auto carve = [&](size_t bytes) {
        void* p = (char*)d_ws + off;
        off += (bytes + 255) & ~(size_t)255;
        return p;
    };
    u16* Wx0t = (u16*)carve((size_t)2048 * 512 * 2);
    u16* Wx1t = (u16*)carve((size_t)2048 * 2048 * 2);
    u16* Wx2t = (u16*)carve((size_t)512 * 2048 * 2);
    u16* Wy0t = (u16*)carve((size_t)TTREAT * 1024 * 512 * 2);
    u16* Wy1t = (u16*)carve((size_t)TTREAT * 512 * 1024 * 2);
    u16* xe   = (u16*)carve((size_t)NROWS * 512 * 2);        // full-N bf16 x_emb
    int* idx  = (int*)carve((size_t)TTREAT * NROWS * 4);
    int* cnt  = (int*)carve(256);
    u16* xbc  = (u16*)carve((size_t)R * 512 * 2);            // chunk x bf16
    u16* h1c  = (u16*)carve((size_t)R * 2048 * 2);
    u16* h2c  = (u16*)carve((size_t)R * 2048 * 2);
    u16* g1c  = (u16*)carve((size_t)R * 1024 * 2);
    u16* g2c  = (u16*)carve((size_t)R * 512 * 2);

    dim3 tb32(32, 8);

    // weight transposes (bf16, [M,K]) — once
    transpose_w<<<dim3(2048 / 32, 512 / 32, 1), tb32, 0, stream>>>(Wx0, Wx0t, 512, 2048);
    transpose_w<<<dim3(2048 / 32, 2048 / 32, 1), tb32, 0, stream>>>(Wx1, Wx1t, 2048, 2048);
    transpose_w<<<dim3(512 / 32, 2048 / 32, 1), tb32, 0, stream>>>(Wx2, Wx2t, 2048, 512);
    transpose_w<<<dim3(1024 / 32, 512 / 32, TTREAT), tb32, 0, stream>>>(Wy0, Wy0t, 512, 1024);
    transpose_w<<<dim3(512 / 32, 1024 / 32, TTREAT), tb32, 0, stream>>>(Wy1, Wy1t, 1024, 512);

    // partition rows by treatment — once
    zero_cnt<<<1, 64, 0, stream>>>(cnt);
    partition_rows<<<NROWS / 256, 256, 0, stream>>>(treat, idx, cnt);

    const int gy = R / 128;   // chunk-local row blocks

    // ---- trunk, chunked over rows ----
    for (int c = 0; c < NCHUNK; ++c) {
        int cS = c * R;
        cvt_f32_bf16<<<(R * 512 / 8 + 255) / 256, 256, 0, stream>>>(
            (const float4*)(x + (size_t)cS * 512), (u16x8*)xbc, R * 512 / 8);
        gemm_bias_relu<false, false><<<dim3(2048 / 128, gy), 256, 0, stream>>>(
            xbc, Wx0t, bx0, h1c, nullptr, nullptr, nullptr, NROWS, cS, R, 512, 2048);
        gemm_bias_relu<false, false><<<dim3(2048 / 128, gy), 256, 0, stream>>>(
            h1c, Wx1t, bx1, h2c, nullptr, nullptr, nullptr, NROWS, cS, R, 2048, 2048);
        gemm_bias_relu<false, true><<<dim3(512 / 128, gy), 256, 0, stream>>>(
            h2c, Wx2t, bx2, xe + (size_t)cS * 512, out_xe + (size_t)cS * 512,
            nullptr, nullptr, NROWS, cS, R, 2048, 512);
    }

    // ---- experts (only the selected treatment's rows), chunked ----
    for (int t = 0; t < TTREAT; ++t) {
        const int* idx_t = idx + (size_t)t * NROWS;
        for (int c = 0; c < NCHUNK; ++c) {
            int cS = c * R;
            gemm_bias_relu<true, false><<<dim3(1024 / 128, gy), 256, 0, stream>>>(
                xe, Wy0t + (size_t)t * 1024 * 512, by0 + (size_t)t * 1024,
                g1c, nullptr, idx_t + cS, cnt + t, NROWS, cS, R, 512, 1024);
            gemm_bias_relu<false, false><<<dim3(512 / 128, gy), 256, 0, stream>>>(
                g1c, Wy1t + (size_t)t * 512 * 1024, by1 + (size_t)t * 512,
                g2c, nullptr, nullptr, cnt + t, NROWS, cS, R, 1024, 512);
            head_kernel<<<R / 4, 256, 0, stream>>>(
                g2c, idx_t + cS, cnt + t, cS, R, Wo + (size_t)t * 512, bo + t, out_y);
        }
    }

    // t_out == softmax over size-1 axis == 1.0 exactly
    ones_kernel<<<NROWS / 256, 256, 0, stream>>>(out_t, NROWS);
}

// Round 4
// 1548.015 us; speedup vs baseline: 1.4066x; 1.0675x over previous
//
#include <hip/hip_runtime.h>
#include <hip/hip_bf16.h>
#include <cstdint>

// Problem constants
#define NROWS 65536
#define TTREAT 2

typedef __bf16 bf16x8 __attribute__((ext_vector_type(8)));
typedef float f32x4 __attribute__((ext_vector_type(4)));
typedef unsigned short u16;
typedef u16 u16x8 __attribute__((ext_vector_type(8)));

#define GLOBAL_AS __attribute__((address_space(1)))
#define LDS_AS __attribute__((address_space(3)))

// ---------------------------------------------------------------------------
// XOR-swizzled bf16 layout: every self-produced [rows,K] bf16 buffer stores
// the 16B chunk j (8 elems) of each 64-elem K-group at position j ^ (row&7).
// Kills the 16-way LDS bank conflict of the 128B-row-stride fragment reads
// (each quad then covers all 32 banks 2-way, which is free — m136), while
// keeping global_load_lds staging contiguous (wave-uniform base + lane*16).
// ---------------------------------------------------------------------------
__device__ __forceinline__ int swz_col(int col, int row) {
    return (col & ~63) | (((((col >> 3) & 7) ^ (row & 7)) << 3)) | (col & 7);
}

__device__ __forceinline__ u16 f32_to_bf16_bits(float f) {
    union { float f; uint32_t u; } v; v.f = f;
    uint32_t u = v.u;
    return (u16)((u + 0x7FFFu + ((u >> 16) & 1u)) >> 16);
}

__device__ __forceinline__ float bf16_bits_to_f32(u16 b) {
    union { uint32_t u; float f; } v; v.u = ((uint32_t)b) << 16;
    return v.f;
}

// ---------------- conversion: f32 -> swizzled bf16 (one 16B chunk/thread) ----
// K must be 512 here (row = chunk>>6).
__global__ void cvt_f32_bf16(const float4* __restrict__ src, u16x8* __restrict__ dst, int n8) {
    int i = blockIdx.x * blockDim.x + threadIdx.x;
    if (i >= n8) return;
    float4 a = src[2 * i], b = src[2 * i + 1];
    u16x8 r;
    r[0] = f32_to_bf16_bits(a.x); r[1] = f32_to_bf16_bits(a.y);
    r[2] = f32_to_bf16_bits(a.z); r[3] = f32_to_bf16_bits(a.w);
    r[4] = f32_to_bf16_bits(b.x); r[5] = f32_to_bf16_bits(b.y);
    r[6] = f32_to_bf16_bits(b.z); r[7] = f32_to_bf16_bits(b.w);
    int row = i >> 6;                                   // K=512 -> 64 chunks/row
    int j = (i & ~7) | ((i ^ row) & 7);                 // swizzle chunk in group
    dst[j] = r;
}

// ---------------- weight transpose: src [K,M] f32 -> dst [M,K] bf16 swizzled -
__global__ void transpose_w(const float* __restrict__ src, u16* __restrict__ dst, int K, int M) {
    __shared__ float tile[32][33];
    size_t boff = (size_t)blockIdx.z * K * M;
    src += boff; dst += boff;
    int m0 = blockIdx.x * 32, k0 = blockIdx.y * 32;
    int tx = threadIdx.x, ty = threadIdx.y;
#pragma unroll
    for (int i = 0; i < 32; i += 8)
        tile[ty + i][tx] = src[(size_t)(k0 + ty + i) * M + m0 + tx];
    __syncthreads();
#pragma unroll
    for (int i = 0; i < 32; i += 8) {
        int row = m0 + ty + i, col = k0 + tx;
        dst[(size_t)row * K + swz_col(col, row)] = f32_to_bf16_bits(tile[tx][ty + i]);
    }
}

// ---------------- partition rows by treatment --------------------------------
__global__ void zero_cnt(int* cnt) {
    if (threadIdx.x < TTREAT) cnt[threadIdx.x] = 0;
}

// Hierarchical: wave ballot -> LDS wave counts -> 1 atomic/treatment/block.
__global__ void partition_rows(const int* __restrict__ treat, int* __restrict__ idx, int* __restrict__ cnt) {
    __shared__ int waveCnt1[4];
    __shared__ int blockBase[2];
    const int tid = threadIdx.x;
    const int i = blockIdx.x * 256 + tid;
    const int wave = tid >> 6, lane = tid & 63;
    const int t = treat[i];
    const unsigned long long m1 = __ballot(t == 1);
    const int n1 = __popcll(m1);
    if (lane == 0) waveCnt1[wave] = n1;
    __syncthreads();
    const int w0 = waveCnt1[0], w1 = waveCnt1[1], w2 = waveCnt1[2], w3 = waveCnt1[3];
    const int tot1 = w0 + w1 + w2 + w3;
    if (tid == 0) blockBase[0] = atomicAdd(&cnt[0], 256 - tot1);
    else if (tid == 64) blockBase[1] = atomicAdd(&cnt[1], tot1);
    __syncthreads();
    int waveOff1 = 0;
    if (wave > 0) waveOff1 += w0;
    if (wave > 1) waveOff1 += w1;
    if (wave > 2) waveOff1 += w2;
    const int below1 = (int)__popcll(m1 & ((1ull << lane) - 1ull));
    int pos;
    if (t == 1) pos = blockBase[1] + waveOff1 + below1;
    else        pos = blockBase[0] + (wave * 64 - waveOff1) + (lane - below1);
    idx[t * NROWS + pos] = i;
}

// ---------------- main GEMM: C = relu(A @ Bt^T + bias) -----------------------
// All bf16 buffers (A, Bt, C) use the swizzled layout. C32 (f32) is logical.
// LDS invariant: slot s of LDS row r holds logical chunk s ^ (r&7).
// 128x128 tile, BK=64, 256 threads (4 waves as 2x2 of 64x64)
template <bool GATHER, bool WRITE_F32>
__global__ void gemm_bias_relu(const u16* __restrict__ A, const u16* __restrict__ Bt,
                               const float* __restrict__ bias,
                               u16* __restrict__ C, float* __restrict__ C32,
                               const int* __restrict__ idx, const int* __restrict__ cntp,
                               int nrows, int chunkStart, int maxRows, int K, int M) {
    int rows = (cntp ? *cntp : nrows) - chunkStart;
    if (rows > maxRows) rows = maxRows;
    int rowBase = blockIdx.y * 128;
    if (rows <= 0 || rowBase >= rows) return;
    int colBase = blockIdx.x * 128;

    __shared__ __align__(16) u16 As[128 * 64];
    __shared__ __align__(16) u16 Bs[128 * 64];

    const int tid = threadIdx.x;
    const int wave = tid >> 6, lane = tid & 63;
    const int quad = lane >> 4, l16 = lane & 15;
    const int wm = wave >> 1, wn = wave & 1;

    // staging geometry: lane handles row r0 (8 lanes/row), chunk (tid&7)
    const int r0 = tid >> 3;          // 0..31 (local row within 32-row slab)
    const int kc = (tid & 7) * 8;     // logical-position chunk offset 0..56

    size_t a_off[4], b_off[4];
#pragma unroll
    for (int it = 0; it < 4; ++it) {
        int r = rowBase + r0 + it * 32;
        if (GATHER) {
            int rc = r < rows ? r : (rows - 1);
            int g = idx[rc];
            // fetch logical chunk (slot ^ (r&7)), stored at position ^ (g&7):
            int kcg = ((((tid & 7) ^ (r & 7) ^ (g & 7)) & 7) * 8);
            a_off[it] = (size_t)g * K + kcg;
        } else {
            // physical parity == local parity: fetch position (tid&7) verbatim
            a_off[it] = (size_t)r * K + kc;
        }
        int c = colBase + r0 + it * 32;   // always < M (M multiple of 128)
        b_off[it] = (size_t)c * K + kc;
    }

    f32x4 acc[4][4] = {};

    for (int k0 = 0; k0 < K; k0 += 64) {
        __syncthreads();
#pragma unroll
        for (int it = 0; it < 4; ++it) {
            __builtin_amdgcn_global_load_lds(
                (const GLOBAL_AS void*)(A + a_off[it] + k0),
                (LDS_AS void*)(&As[(it * 256 + wave * 64) * 8]), 16, 0, 0);
            __builtin_amdgcn_global_load_lds(
                (const GLOBAL_AS void*)(Bt + b_off[it] + k0),
                (LDS_AS void*)(&Bs[(it * 256 + wave * 64) * 8]), 16, 0, 0);
        }
        __syncthreads();
#pragma unroll
        for (int kk = 0; kk < 2; ++kk) {
            bf16x8 aF[4], bF[4];
            // logical chunk kk*4+quad lives at slot (kk*4+quad) ^ (row&7);
            // row&7 == l16&7 for every fragment row (row = base16*16 + l16).
            const int csw = ((kk * 4 + quad) ^ (l16 & 7)) * 8;
#pragma unroll
            for (int mi = 0; mi < 4; ++mi)
                aF[mi] = *(const bf16x8*)&As[(wm * 64 + mi * 16 + l16) * 64 + csw];
#pragma unroll
            for (int ni = 0; ni < 4; ++ni)
                bF[ni] = *(const bf16x8*)&Bs[(wn * 64 + ni * 16 + l16) * 64 + csw];
#pragma unroll
            for (int mi = 0; mi < 4; ++mi)
#pragma unroll
                for (int ni = 0; ni < 4; ++ni)
                    acc[mi][ni] = __builtin_amdgcn_mfma_f32_16x16x32_bf16(
                        aF[mi], bF[ni], acc[mi][ni], 0, 0, 0);
        }
    }

    // epilogue: bias + relu; bf16 C swizzled, f32 C32 logical
    float bv[4];
#pragma unroll
    for (int ni = 0; ni < 4; ++ni) bv[ni] = bias[colBase + wn * 64 + ni * 16 + l16];

#pragma unroll
    for (int mi = 0; mi < 4; ++mi) {
        int rloc = rowBase + wm * 64 + mi * 16 + quad * 4;
#pragma unroll
        for (int ni = 0; ni < 4; ++ni) {
            int col = colBase + wn * 64 + ni * 16 + l16;
#pragma unroll
            for (int r = 0; r < 4; ++r) {
                int row = rloc + r;
                if (row < rows) {
                    float v = acc[mi][ni][r] + bv[ni];
                    v = v > 0.f ? v : 0.f;
                    C[(size_t)row * M + swz_col(col, row)] = f32_to_bf16_bits(v);
                    if (WRITE_F32) C32[(size_t)row * M + col] = v;
                }
            }
        }
    }
}

// ---------------- head: y[idx[pos]] = dot(g2[pos], Wo) + bo ------------------
// g2 is swizzled; lane reads *position* lane (contiguous) and indexes Wo by
// the logical chunk that position holds.
__global__ void head_kernel(const u16* __restrict__ g2, const int* __restrict__ idx,
                            const int* __restrict__ cntp, int chunkStart, int maxRows,
                            const float* __restrict__ Wo,
                            const float* __restrict__ bo, float* __restrict__ y) {
    int rows = *cntp - chunkStart;
    if (rows > maxRows) rows = maxRows;
    int wave = threadIdx.x >> 6, lane = threadIdx.x & 63;
    int pos = blockIdx.x * 4 + wave;
    if (pos >= rows) return;
    const u16* grow = g2 + (size_t)pos * 512;
    u16x8 gv = *(const u16x8*)&grow[lane * 8];
    int logical = (lane & ~7) | ((lane ^ pos) & 7);     // chunk held at this pos
    const float4* w4 = (const float4*)Wo + logical * 2;
    float4 w0 = w4[0], w1 = w4[1];
    float s = 0.f;
    s += bf16_bits_to_f32(gv[0]) * w0.x + bf16_bits_to_f32(gv[1]) * w0.y;
    s += bf16_bits_to_f32(gv[2]) * w0.z + bf16_bits_to_f32(gv[3]) * w0.w;
    s += bf16_bits_to_f32(gv[4]) * w1.x + bf16_bits_to_f32(gv[5]) * w1.y;
    s += bf16_bits_to_f32(gv[6]) * w1.z + bf16_bits_to_f32(gv[7]) * w1.w;
#pragma unroll
    for (int off = 32; off > 0; off >>= 1) s += __shfl_down(s, off);
    if (lane == 0) y[idx[pos]] = s + bo[0];
}

// ---------------- t_out: softmax over size-1 axis == 1.0 ---------------------
__global__ void ones_kernel(float* __restrict__ dst, int n) {
    int i = blockIdx.x * 256 + threadIdx.x;
    if (i < n) dst[i] = 1.0f;
}

extern "C" void kernel_launch(void* const* d_in, const int* in_sizes, int n_in,
                              void* d_out, int out_size, void* d_ws, size_t ws_size,
                              hipStream_t stream) {
    const float* x   = (const float*)d_in[0];
    const int* treat = (const int*)d_in[1];
    const float* Wx0 = (const float*)d_in[2];
    const float* bx0 = (const float*)d_in[3];
    const float* Wx1 = (const float*)d_in[4];
    const float* bx1 = (const float*)d_in[5];
    const float* Wx2 = (const float*)d_in[6];
    const float* bx2 = (const float*)d_in[7];
    const float* Wy0 = (const float*)d_in[8];
    const float* by0 = (const float*)d_in[9];
    const float* Wy1 = (const float*)d_in[10];
    const float* by1 = (const float*)d_in[11];
    const float* Wo  = (const float*)d_in[12];
    const float* bo  = (const float*)d_in[13];
    // Wt (14), bt (15) unused: softmax over size-1 axis == 1 exactly

    float* out_y  = (float*)d_out;                       // [N]
    float* out_xe = out_y + NROWS;                       // [N, 512]
    float* out_t  = out_xe + (size_t)NROWS * 512;        // [N]

    // ---- choose row-chunk size R from ws_size (deterministic per process) ----
    const size_t FIXED = ((size_t)(2048 * 512 + 2048 * 2048 + 512 * 2048
                          + TTREAT * 1024 * 512 + TTREAT * 512 * 1024
                          + (size_t)NROWS * 512) * 2)                 // bf16 bufs
                          + (size_t)TTREAT * NROWS * 4 + (1 << 20);   // idx + slack
    int R = 512;
    const int cands[6] = {16384, 8192, 4096, 2048, 1024, 512};
    for (int ci = 0; ci < 6; ++ci) {
        if (FIXED + (size_t)cands[ci] * 12288 <= ws_size) { R = cands[ci]; break; }
    }
    const int NCHUNK = NROWS / R;

    // ---- workspace carve-up ----
    size_t off = 0;
    auto carve = [&](size_t bytes) {
        void* p = (char*)d_ws + off;
        off += (bytes + 255) & ~(size_t)255;
        return p;
    };
    u16* Wx0t = (u16*)carve((size_t)2048 * 512 * 2);
    u16* Wx1t = (u16*)carve((size_t)2048 * 2048 * 2);
    u16* Wx2t = (u16*)carve((size_t)512 * 2048 * 2);
    u16* Wy0t = (u16*)carve((size_t)TTREAT * 1024 * 512 * 2);
    u16* Wy1t = (u16*)carve((size_t)TTREAT * 512 * 1024 * 2);
    u16* xe   = (u16*)carve((size_t)NROWS * 512 * 2);        // full-N bf16 x_emb
    int* idx  = (int*)carve((size_t)TTREAT * NROWS * 4);
    int* cnt  = (int*)carve(256);
    u16* xbc  = (u16*)carve((size_t)R * 512 * 2);            // chunk x bf16
    u16* h1c  = (u16*)carve((size_t)R * 2048 * 2);
    u16* h2c  = (u16*)carve((size_t)R * 2048 * 2);
    u16* g1c  = (u16*)carve((size_t)R * 1024 * 2);
    u16* g2c  = (u16*)carve((size_t)R * 512 * 2);

    dim3 tb32(32, 8);

    // weight transposes (bf16, [M,K], swizzled) — once
    transpose_w<<<dim3(2048 / 32, 512 / 32, 1), tb32, 0, stream>>>(Wx0, Wx0t, 512, 2048);
    transpose_w<<<dim3(2048 / 32, 2048 / 32, 1), tb32, 0, stream>>>(Wx1, Wx1t, 2048, 2048);
    transpose_w<<<dim3(512 / 32, 2048 / 32, 1), tb32, 0, stream>>>(Wx2, Wx2t, 2048, 512);
    transpose_w<<<dim3(1024 / 32, 512 / 32, TTREAT), tb32, 0, stream>>>(Wy0, Wy0t, 512, 1024);
    transpose_w<<<dim3(512 / 32, 1024 / 32, TTREAT), tb32, 0, stream>>>(Wy1, Wy1t, 1024, 512);

    // partition rows by treatment — once
    zero_cnt<<<1, 64, 0, stream>>>(cnt);
    partition_rows<<<NROWS / 256, 256, 0, stream>>>(treat, idx, cnt);

    const int gy = R / 128;   // chunk-local row blocks

    // ---- trunk, chunked over rows ----
    for (int c = 0; c < NCHUNK; ++c) {
        int cS = c * R;
        cvt_f32_bf16<<<(R * 512 / 8 + 255) / 256, 256, 0, stream>>>(
            (const float4*)(x + (size_t)cS * 512), (u16x8*)xbc, R * 512 / 8);
        gemm_bias_relu<false, false><<<dim3(2048 / 128, gy), 256, 0, stream>>>(
            xbc, Wx0t, bx0, h1c, nullptr, nullptr, nullptr, NROWS, cS, R, 512, 2048);
        gemm_bias_relu<false, false><<<dim3(2048 / 128, gy), 256, 0, stream>>>(
            h1c, Wx1t, bx1, h2c, nullptr, nullptr, nullptr, NROWS, cS, R, 2048, 2048);
        gemm_bias_relu<false, true><<<dim3(512 / 128, gy), 256, 0, stream>>>(
            h2c, Wx2t, bx2, xe + (size_t)cS * 512, out_xe + (size_t)cS * 512,
            nullptr, nullptr, NROWS, cS, R, 2048, 512);
    }

    // ---- experts (only the selected treatment's rows), chunked ----
    for (int t = 0; t < TTREAT; ++t) {
        const int* idx_t = idx + (size_t)t * NROWS;
        for (int c = 0; c < NCHUNK; ++c) {
            int cS = c * R;
            gemm_bias_relu<true, false><<<dim3(1024 / 128, gy), 256, 0, stream>>>(
                xe, Wy0t + (size_t)t * 1024 * 512, by0 + (size_t)t * 1024,
                g1c, nullptr, idx_t + cS, cnt + t, NROWS, cS, R, 512, 1024);
            gemm_bias_relu<false, false><<<dim3(512 / 128, gy), 256, 0, stream>>>(
                g1c, Wy1t + (size_t)t * 512 * 1024, by1 + (size_t)t * 512,
                g2c, nullptr, nullptr, cnt + t, NROWS, cS, R, 1024, 512);
            head_kernel<<<R / 4, 256, 0, stream>>>(
                g2c, idx_t + cS, cnt + t, cS, R, Wo + (size_t)t * 512, bo + t, out_y);
        }
    }

    // t_out == softmax over size-1 axis == 1.0 exactly
    ones_kernel<<<NROWS / 256, 256, 0, stream>>>(out_t, NROWS);
}

// Round 5
// 1488.671 us; speedup vs baseline: 1.4626x; 1.0399x over previous
//
#include <hip/hip_runtime.h>
#include <hip/hip_bf16.h>
#include <cstdint>

// Problem constants
#define NROWS 65536
#define TTREAT 2

typedef __bf16 bf16x8 __attribute__((ext_vector_type(8)));
typedef float f32x4 __attribute__((ext_vector_type(4)));
typedef unsigned short u16;
typedef u16 u16x8 __attribute__((ext_vector_type(8)));

#define GLOBAL_AS __attribute__((address_space(1)))
#define LDS_AS __attribute__((address_space(3)))

// ---------------------------------------------------------------------------
// XOR-swizzled bf16 layout: every self-produced [rows,K] bf16 buffer stores
// the 16B chunk j (8 elems) of each 64-elem K-group at position j ^ (row&7).
// Kills the 16-way LDS bank conflict of the 128B-row-stride fragment reads
// (verified R4: SQ_LDS_BANK_CONFLICT 5.03e7 -> 0, MfmaUtil 35->45%).
// ---------------------------------------------------------------------------
__device__ __forceinline__ int swz_col(int col, int row) {
    return (col & ~63) | (((((col >> 3) & 7) ^ (row & 7)) << 3)) | (col & 7);
}

__device__ __forceinline__ u16 f32_to_bf16_bits(float f) {
    union { float f; uint32_t u; } v; v.f = f;
    uint32_t u = v.u;
    return (u16)((u + 0x7FFFu + ((u >> 16) & 1u)) >> 16);
}

// ---------------- conversion: f32 -> swizzled bf16 (one 16B chunk/thread) ----
// K must be 512 here (row = chunk>>6).
__global__ void cvt_f32_bf16(const float4* __restrict__ src, u16x8* __restrict__ dst, int n8) {
    int i = blockIdx.x * blockDim.x + threadIdx.x;
    if (i >= n8) return;
    float4 a = src[2 * i], b = src[2 * i + 1];
    u16x8 r;
    r[0] = f32_to_bf16_bits(a.x); r[1] = f32_to_bf16_bits(a.y);
    r[2] = f32_to_bf16_bits(a.z); r[3] = f32_to_bf16_bits(a.w);
    r[4] = f32_to_bf16_bits(b.x); r[5] = f32_to_bf16_bits(b.y);
    r[6] = f32_to_bf16_bits(b.z); r[7] = f32_to_bf16_bits(b.w);
    int row = i >> 6;                                   // K=512 -> 64 chunks/row
    int j = (i & ~7) | ((i ^ row) & 7);                 // swizzle chunk in group
    dst[j] = r;
}

// ---------------- weight transpose: src [K,M] f32 -> dst [M,K] bf16 swizzled -
__global__ void transpose_w(const float* __restrict__ src, u16* __restrict__ dst, int K, int M) {
    __shared__ float tile[32][33];
    size_t boff = (size_t)blockIdx.z * K * M;
    src += boff; dst += boff;
    int m0 = blockIdx.x * 32, k0 = blockIdx.y * 32;
    int tx = threadIdx.x, ty = threadIdx.y;
#pragma unroll
    for (int i = 0; i < 32; i += 8)
        tile[ty + i][tx] = src[(size_t)(k0 + ty + i) * M + m0 + tx];
    __syncthreads();
#pragma unroll
    for (int i = 0; i < 32; i += 8) {
        int row = m0 + ty + i, col = k0 + tx;
        dst[(size_t)row * K + swz_col(col, row)] = f32_to_bf16_bits(tile[tx][ty + i]);
    }
}

// ---------------- partition rows by treatment --------------------------------
__global__ void zero_cnt(int* cnt) {
    if (threadIdx.x < TTREAT) cnt[threadIdx.x] = 0;
}

// Hierarchical: wave ballot -> LDS wave counts -> 1 atomic/treatment/block.
__global__ void partition_rows(const int* __restrict__ treat, int* __restrict__ idx, int* __restrict__ cnt) {
    __shared__ int waveCnt1[4];
    __shared__ int blockBase[2];
    const int tid = threadIdx.x;
    const int i = blockIdx.x * 256 + tid;
    const int wave = tid >> 6, lane = tid & 63;
    const int t = treat[i];
    const unsigned long long m1 = __ballot(t == 1);
    const int n1 = __popcll(m1);
    if (lane == 0) waveCnt1[wave] = n1;
    __syncthreads();
    const int w0 = waveCnt1[0], w1 = waveCnt1[1], w2 = waveCnt1[2], w3 = waveCnt1[3];
    const int tot1 = w0 + w1 + w2 + w3;
    if (tid == 0) blockBase[0] = atomicAdd(&cnt[0], 256 - tot1);
    else if (tid == 64) blockBase[1] = atomicAdd(&cnt[1], tot1);
    __syncthreads();
    int waveOff1 = 0;
    if (wave > 0) waveOff1 += w0;
    if (wave > 1) waveOff1 += w1;
    if (wave > 2) waveOff1 += w2;
    const int below1 = (int)__popcll(m1 & ((1ull << lane) - 1ull));
    int pos;
    if (t == 1) pos = blockBase[1] + waveOff1 + below1;
    else        pos = blockBase[0] + (wave * 64 - waveOff1) + (lane - below1);
    idx[t * NROWS + pos] = i;
}

// ---------------- output init: y[i] = bo[treat[i]], t_out[i] = 1.0 -----------
// (softmax over size-1 axis == 1 exactly; head bias folded into y init so the
// fused-head epilogue only atomicAdds partial dots.)
__global__ void init_outputs(const int* __restrict__ treat, const float* __restrict__ bo,
                             float* __restrict__ y, float* __restrict__ t_out) {
    int i = blockIdx.x * 256 + threadIdx.x;
    if (i < NROWS) { y[i] = bo[treat[i]]; t_out[i] = 1.0f; }
}

// ---------------- main GEMM: C = relu(A @ Bt^T + bias) -----------------------
// All bf16 buffers (A, Bt, C) use the swizzled layout. C32 (f32) is logical.
// LDS invariant: slot s of LDS row r holds logical chunk s ^ (r&7).
// FUSE_HEAD: no C write; instead per-row partial dot with Wo over this block's
// 128 cols, reduced across lanes (width-16 shfl matches C-layout col=l16),
// atomicAdd'ed into y[idx[row]]. 8 atomics/row total, distinct addresses.
// 128x128 tile, BK=64, 256 threads (4 waves as 2x2 of 64x64)
template <bool GATHER, bool WRITE_F32, bool FUSE_HEAD>
__global__ void gemm_bias_relu(const u16* __restrict__ A, const u16* __restrict__ Bt,
                               const float* __restrict__ bias,
                               u16* __restrict__ C, float* __restrict__ C32,
                               const int* __restrict__ idx, const int* __restrict__ cntp,
                               int nrows, int chunkStart, int maxRows, int K, int M,
                               const float* __restrict__ Wo, float* __restrict__ y) {
    int rows = (cntp ? *cntp : nrows) - chunkStart;
    if (rows > maxRows) rows = maxRows;
    int rowBase = blockIdx.y * 128;
    if (rows <= 0 || rowBase >= rows) return;
    int colBase = blockIdx.x * 128;

    __shared__ __align__(16) u16 As[128 * 64];
    __shared__ __align__(16) u16 Bs[128 * 64];

    const int tid = threadIdx.x;
    const int wave = tid >> 6, lane = tid & 63;
    const int quad = lane >> 4, l16 = lane & 15;
    const int wm = wave >> 1, wn = wave & 1;

    // staging geometry: lane handles row r0 (8 lanes/row), chunk (tid&7)
    const int r0 = tid >> 3;          // 0..31 (local row within 32-row slab)
    const int kc = (tid & 7) * 8;     // logical-position chunk offset 0..56

    size_t a_off[4], b_off[4];
#pragma unroll
    for (int it = 0; it < 4; ++it) {
        int r = rowBase + r0 + it * 32;
        if (GATHER) {
            int rc = r < rows ? r : (rows - 1);
            int g = idx[rc];
            // fetch logical chunk (slot ^ (r&7)), stored at position ^ (g&7):
            int kcg = ((((tid & 7) ^ (r & 7) ^ (g & 7)) & 7) * 8);
            a_off[it] = (size_t)g * K + kcg;
        } else {
            // physical parity == local parity: fetch position (tid&7) verbatim
            a_off[it] = (size_t)r * K + kc;
        }
        int c = colBase + r0 + it * 32;   // always < M (M multiple of 128)
        b_off[it] = (size_t)c * K + kc;
    }

    f32x4 acc[4][4] = {};

    for (int k0 = 0; k0 < K; k0 += 64) {
        __syncthreads();
#pragma unroll
        for (int it = 0; it < 4; ++it) {
            __builtin_amdgcn_global_load_lds(
                (const GLOBAL_AS void*)(A + a_off[it] + k0),
                (LDS_AS void*)(&As[(it * 256 + wave * 64) * 8]), 16, 0, 0);
            __builtin_amdgcn_global_load_lds(
                (const GLOBAL_AS void*)(Bt + b_off[it] + k0),
                (LDS_AS void*)(&Bs[(it * 256 + wave * 64) * 8]), 16, 0, 0);
        }
        __syncthreads();
#pragma unroll
        for (int kk = 0; kk < 2; ++kk) {
            bf16x8 aF[4], bF[4];
            // logical chunk kk*4+quad lives at slot (kk*4+quad) ^ (row&7);
            // row&7 == l16&7 for every fragment row (row = base16*16 + l16).
            const int csw = ((kk * 4 + quad) ^ (l16 & 7)) * 8;
#pragma unroll
            for (int mi = 0; mi < 4; ++mi)
                aF[mi] = *(const bf16x8*)&As[(wm * 64 + mi * 16 + l16) * 64 + csw];
#pragma unroll
            for (int ni = 0; ni < 4; ++ni)
                bF[ni] = *(const bf16x8*)&Bs[(wn * 64 + ni * 16 + l16) * 64 + csw];
#pragma unroll
            for (int mi = 0; mi < 4; ++mi)
#pragma unroll
                for (int ni = 0; ni < 4; ++ni)
                    acc[mi][ni] = __builtin_amdgcn_mfma_f32_16x16x32_bf16(
                        aF[mi], bF[ni], acc[mi][ni], 0, 0, 0);
        }
    }

    // epilogue: bias + relu
    float bv[4];
#pragma unroll
    for (int ni = 0; ni < 4; ++ni) bv[ni] = bias[colBase + wn * 64 + ni * 16 + l16];

    if (FUSE_HEAD) {
        float wv[4];
#pragma unroll
        for (int ni = 0; ni < 4; ++ni) wv[ni] = Wo[colBase + wn * 64 + ni * 16 + l16];
        float hs[4][4];   // [mi][r] per-lane partial dot over this lane's 4 cols
#pragma unroll
        for (int mi = 0; mi < 4; ++mi)
#pragma unroll
            for (int r = 0; r < 4; ++r) {
                float s = 0.f;
#pragma unroll
                for (int ni = 0; ni < 4; ++ni) {
                    float v = acc[mi][ni][r] + bv[ni];
                    v = v > 0.f ? v : 0.f;
                    s += v * wv[ni];
                }
                hs[mi][r] = s;
            }
        // reduce across the 16 lanes of each quad (C-layout: col = l16)
#pragma unroll
        for (int mi = 0; mi < 4; ++mi)
#pragma unroll
            for (int r = 0; r < 4; ++r) {
                float s = hs[mi][r];
                s += __shfl_down(s, 8, 16);
                s += __shfl_down(s, 4, 16);
                s += __shfl_down(s, 2, 16);
                s += __shfl_down(s, 1, 16);
                if (l16 == 0) {
                    int row = rowBase + wm * 64 + mi * 16 + quad * 4 + r;
                    if (row < rows) atomicAdd(&y[idx[row]], s);
                }
            }
    } else {
#pragma unroll
        for (int mi = 0; mi < 4; ++mi) {
            int rloc = rowBase + wm * 64 + mi * 16 + quad * 4;
#pragma unroll
            for (int ni = 0; ni < 4; ++ni) {
                int col = colBase + wn * 64 + ni * 16 + l16;
#pragma unroll
                for (int r = 0; r < 4; ++r) {
                    int row = rloc + r;
                    if (row < rows) {
                        float v = acc[mi][ni][r] + bv[ni];
                        v = v > 0.f ? v : 0.f;
                        C[(size_t)row * M + swz_col(col, row)] = f32_to_bf16_bits(v);
                        if (WRITE_F32) C32[(size_t)row * M + col] = v;
                    }
                }
            }
        }
    }
}

extern "C" void kernel_launch(void* const* d_in, const int* in_sizes, int n_in,
                              void* d_out, int out_size, void* d_ws, size_t ws_size,
                              hipStream_t stream) {
    const float* x   = (const float*)d_in[0];
    const int* treat = (const int*)d_in[1];
    const float* Wx0 = (const float*)d_in[2];
    const float* bx0 = (const float*)d_in[3];
    const float* Wx1 = (const float*)d_in[4];
    const float* bx1 = (const float*)d_in[5];
    const float* Wx2 = (const float*)d_in[6];
    const float* bx2 = (const float*)d_in[7];
    const float* Wy0 = (const float*)d_in[8];
    const float* by0 = (const float*)d_in[9];
    const float* Wy1 = (const float*)d_in[10];
    const float* by1 = (const float*)d_in[11];
    const float* Wo  = (const float*)d_in[12];
    const float* bo  = (const float*)d_in[13];
    // Wt (14), bt (15) unused: softmax over size-1 axis == 1 exactly

    float* out_y  = (float*)d_out;                       // [N]
    float* out_xe = out_y + NROWS;                       // [N, 512]
    float* out_t  = out_xe + (size_t)NROWS * 512;        // [N]

    // ---- choose row-chunk size R from ws_size (deterministic per process) ----
    const size_t FIXED = ((size_t)(2048 * 512 + 2048 * 2048 + 512 * 2048
                          + TTREAT * 1024 * 512 + TTREAT * 512 * 1024
                          + (size_t)NROWS * 512) * 2)                 // bf16 bufs
                          + (size_t)TTREAT * NROWS * 4 + (1 << 20);   // idx + slack
    int R = 512;
    const int cands[8] = {65536, 32768, 16384, 8192, 4096, 2048, 1024, 512};
    for (int ci = 0; ci < 8; ++ci) {
        // variable/row: xbc 1024 + h1c 4096 + h2c 4096 + g1c 2048 = 11264 B
        if (FIXED + (size_t)cands[ci] * 11264 <= ws_size) { R = cands[ci]; break; }
    }
    const int NCHUNK = NROWS / R;

    // ---- workspace carve-up ----
    size_t off = 0;
    auto carve = [&](size_t bytes) {
        void* p = (char*)d_ws + off;
        off += (bytes + 255) & ~(size_t)255;
        return p;
    };
    u16* Wx0t = (u16*)carve((size_t)2048 * 512 * 2);
    u16* Wx1t = (u16*)carve((size_t)2048 * 2048 * 2);
    u16* Wx2t = (u16*)carve((size_t)512 * 2048 * 2);
    u16* Wy0t = (u16*)carve((size_t)TTREAT * 1024 * 512 * 2);
    u16* Wy1t = (u16*)carve((size_t)TTREAT * 512 * 1024 * 2);
    u16* xe   = (u16*)carve((size_t)NROWS * 512 * 2);        // full-N bf16 x_emb
    int* idx  = (int*)carve((size_t)TTREAT * NROWS * 4);
    int* cnt  = (int*)carve(256);
    u16* xbc  = (u16*)carve((size_t)R * 512 * 2);            // chunk x bf16
    u16* h1c  = (u16*)carve((size_t)R * 2048 * 2);
    u16* h2c  = (u16*)carve((size_t)R * 2048 * 2);
    u16* g1c  = (u16*)carve((size_t)R * 1024 * 2);

    dim3 tb32(32, 8);

    // weight transposes (bf16, [M,K], swizzled) — once
    transpose_w<<<dim3(2048 / 32, 512 / 32, 1), tb32, 0, stream>>>(Wx0, Wx0t, 512, 2048);
    transpose_w<<<dim3(2048 / 32, 2048 / 32, 1), tb32, 0, stream>>>(Wx1, Wx1t, 2048, 2048);
    transpose_w<<<dim3(512 / 32, 2048 / 32, 1), tb32, 0, stream>>>(Wx2, Wx2t, 2048, 512);
    transpose_w<<<dim3(1024 / 32, 512 / 32, TTREAT), tb32, 0, stream>>>(Wy0, Wy0t, 512, 1024);
    transpose_w<<<dim3(512 / 32, 1024 / 32, TTREAT), tb32, 0, stream>>>(Wy1, Wy1t, 1024, 512);

    // partition rows by treatment — once
    zero_cnt<<<1, 64, 0, stream>>>(cnt);
    partition_rows<<<NROWS / 256, 256, 0, stream>>>(treat, idx, cnt);

    // output init (y = head bias, t_out = 1.0)
    init_outputs<<<NROWS / 256, 256, 0, stream>>>(treat, bo, out_y, out_t);

    const int gy = R / 128;   // chunk-local row blocks

    // ---- trunk, chunked over rows ----
    for (int c = 0; c < NCHUNK; ++c) {
        int cS = c * R;
        cvt_f32_bf16<<<(R * 512 / 8 + 255) / 256, 256, 0, stream>>>(
            (const float4*)(x + (size_t)cS * 512), (u16x8*)xbc, R * 512 / 8);
        gemm_bias_relu<false, false, false><<<dim3(2048 / 128, gy), 256, 0, stream>>>(
            xbc, Wx0t, bx0, h1c, nullptr, nullptr, nullptr, NROWS, cS, R, 512, 2048,
            nullptr, nullptr);
        gemm_bias_relu<false, false, false><<<dim3(2048 / 128, gy), 256, 0, stream>>>(
            h1c, Wx1t, bx1, h2c, nullptr, nullptr, nullptr, NROWS, cS, R, 2048, 2048,
            nullptr, nullptr);
        gemm_bias_relu<false, true, false><<<dim3(512 / 128, gy), 256, 0, stream>>>(
            h2c, Wx2t, bx2, xe + (size_t)cS * 512, out_xe + (size_t)cS * 512,
            nullptr, nullptr, NROWS, cS, R, 2048, 512, nullptr, nullptr);
    }

    // ---- experts (only the selected treatment's rows), chunked ----
    for (int t = 0; t < TTREAT; ++t) {
        const int* idx_t = idx + (size_t)t * NROWS;
        for (int c = 0; c < NCHUNK; ++c) {
            int cS = c * R;
            gemm_bias_relu<true, false, false><<<dim3(1024 / 128, gy), 256, 0, stream>>>(
                xe, Wy0t + (size_t)t * 1024 * 512, by0 + (size_t)t * 1024,
                g1c, nullptr, idx_t + cS, cnt + t, NROWS, cS, R, 512, 1024,
                nullptr, nullptr);
            // expert layer 1 with fused output head (no C write; atomic dots)
            gemm_bias_relu<false, false, true><<<dim3(512 / 128, gy), 256, 0, stream>>>(
                g1c, Wy1t + (size_t)t * 512 * 1024, by1 + (size_t)t * 512,
                nullptr, nullptr, idx_t + cS, cnt + t, NROWS, cS, R, 1024, 512,
                Wo + (size_t)t * 512, out_y);
        }
    }
}